// Round 1
// baseline (2275.089 us; speedup 1.0000x reference)
//
#include <hip/hip_runtime.h>

// Attention_65807488909977: bilinear attention, f32 baseline (vector ALU).
// B=8, LQ=LK=2048, D=DV=1024.
//   qW     = query @ W                  [8,2048,1024]   (staged in d_out ctx region)
//   scores = qW @ key^T (+bias)         [8,2048,2048]   (bias is a scalar shift ->
//                                                        softmax-invariant -> skipped)
//   weights= softmax(scores, -1)        -> d_out[0 .. 33554432)
//   ctx    = weights @ value            -> d_out[33554432 .. 50331648)  (overwrites qW)

#define BM 128
#define BN 128
#define BK 16
#define TM 8
#define TN 8

// C[b] = A[b] @ B[b]   (row-major; strides sA/sB/sC per blockIdx.z batch)
__global__ __launch_bounds__(256) void gemm_nn(
    const float* __restrict__ A, const float* __restrict__ B, float* __restrict__ C,
    int M, int N, int K, long sA, long sB, long sC)
{
    __shared__ float As[BK][BM];   // transposed A tile
    __shared__ float Bs[BK][BN];

    const int bz = blockIdx.z;
    A += (long)bz * sA;  B += (long)bz * sB;  C += (long)bz * sC;

    const int m0 = blockIdx.y * BM;
    const int n0 = blockIdx.x * BN;
    const int tid = threadIdx.x;
    const int tn = tid & 15, tm = tid >> 4;

    float acc[TM][TN];
    #pragma unroll
    for (int i = 0; i < TM; ++i)
        #pragma unroll
        for (int j = 0; j < TN; ++j) acc[i][j] = 0.f;

    for (int k0 = 0; k0 < K; k0 += BK) {
        // A tile: 128 rows x 16 cols = 2 float4 per thread
        float4 av[2]; float4 bv[2];
        #pragma unroll
        for (int it = 0; it < 2; ++it) {
            int ar = (tid >> 2) + it * 64;      // 0..127
            int ac = (tid & 3) * 4;             // 0..12
            av[it] = *(const float4*)&A[(long)(m0 + ar) * K + k0 + ac];
            int br = (tid >> 5) + it * 8;       // 0..15
            int bc = (tid & 31) * 4;            // 0..124
            bv[it] = *(const float4*)&B[(long)(k0 + br) * N + n0 + bc];
        }
        __syncthreads();
        #pragma unroll
        for (int it = 0; it < 2; ++it) {
            int ar = (tid >> 2) + it * 64;
            int ac = (tid & 3) * 4;
            As[ac + 0][ar] = av[it].x;
            As[ac + 1][ar] = av[it].y;
            As[ac + 2][ar] = av[it].z;
            As[ac + 3][ar] = av[it].w;
            int br = (tid >> 5) + it * 8;
            int bc = (tid & 31) * 4;
            *(float4*)&Bs[br][bc] = bv[it];
        }
        __syncthreads();
        #pragma unroll
        for (int kk = 0; kk < BK; ++kk) {
            float a[TM], b[TN];
            *(float4*)&a[0] = *(const float4*)&As[kk][tm * TM];
            *(float4*)&a[4] = *(const float4*)&As[kk][tm * TM + 4];
            *(float4*)&b[0] = *(const float4*)&Bs[kk][tn * TN];
            *(float4*)&b[4] = *(const float4*)&Bs[kk][tn * TN + 4];
            #pragma unroll
            for (int i = 0; i < TM; ++i)
                #pragma unroll
                for (int j = 0; j < TN; ++j)
                    acc[i][j] += a[i] * b[j];
        }
    }

    #pragma unroll
    for (int i = 0; i < TM; ++i) {
        float* c = &C[(long)(m0 + tm * TM + i) * N + n0 + tn * TN];
        *(float4*)&c[0] = *(const float4*)&acc[i][0];
        *(float4*)&c[4] = *(const float4*)&acc[i][4];
    }
}

// C[b] = A[b] @ Bt[b]^T   (Bt is [N, K] row-major -> both operands K-contiguous)
__global__ __launch_bounds__(256) void gemm_nt(
    const float* __restrict__ A, const float* __restrict__ Bt, float* __restrict__ C,
    int M, int N, int K, long sA, long sB, long sC)
{
    __shared__ float As[BK][BM];
    __shared__ float Bs[BK][BN];

    const int bz = blockIdx.z;
    A += (long)bz * sA;  Bt += (long)bz * sB;  C += (long)bz * sC;

    const int m0 = blockIdx.y * BM;
    const int n0 = blockIdx.x * BN;
    const int tid = threadIdx.x;
    const int tn = tid & 15, tm = tid >> 4;

    float acc[TM][TN];
    #pragma unroll
    for (int i = 0; i < TM; ++i)
        #pragma unroll
        for (int j = 0; j < TN; ++j) acc[i][j] = 0.f;

    for (int k0 = 0; k0 < K; k0 += BK) {
        float4 av[2]; float4 bv[2];
        #pragma unroll
        for (int it = 0; it < 2; ++it) {
            int ar = (tid >> 2) + it * 64;
            int ac = (tid & 3) * 4;
            av[it] = *(const float4*)&A[(long)(m0 + ar) * K + k0 + ac];
            bv[it] = *(const float4*)&Bt[(long)(n0 + ar) * K + k0 + ac];
        }
        __syncthreads();
        #pragma unroll
        for (int it = 0; it < 2; ++it) {
            int ar = (tid >> 2) + it * 64;
            int ac = (tid & 3) * 4;
            As[ac + 0][ar] = av[it].x;
            As[ac + 1][ar] = av[it].y;
            As[ac + 2][ar] = av[it].z;
            As[ac + 3][ar] = av[it].w;
            Bs[ac + 0][ar] = bv[it].x;
            Bs[ac + 1][ar] = bv[it].y;
            Bs[ac + 2][ar] = bv[it].z;
            Bs[ac + 3][ar] = bv[it].w;
        }
        __syncthreads();
        #pragma unroll
        for (int kk = 0; kk < BK; ++kk) {
            float a[TM], b[TN];
            *(float4*)&a[0] = *(const float4*)&As[kk][tm * TM];
            *(float4*)&a[4] = *(const float4*)&As[kk][tm * TM + 4];
            *(float4*)&b[0] = *(const float4*)&Bs[kk][tn * TN];
            *(float4*)&b[4] = *(const float4*)&Bs[kk][tn * TN + 4];
            #pragma unroll
            for (int i = 0; i < TM; ++i)
                #pragma unroll
                for (int j = 0; j < TN; ++j)
                    acc[i][j] += a[i] * b[j];
        }
    }

    #pragma unroll
    for (int i = 0; i < TM; ++i) {
        float* c = &C[(long)(m0 + tm * TM + i) * N + n0 + tn * TN];
        *(float4*)&c[0] = *(const float4*)&acc[i][0];
        *(float4*)&c[4] = *(const float4*)&acc[i][4];
    }
}

// In-place row softmax; one block per row of L=2048 floats (8 per thread).
__global__ __launch_bounds__(256) void softmax_rows(float* __restrict__ S, int L)
{
    __shared__ float red[256];
    const int tid = threadIdx.x;
    float4* p4 = (float4*)(S + (size_t)blockIdx.x * L);

    float4 x0 = p4[tid];
    float4 x1 = p4[tid + 256];

    float m = fmaxf(fmaxf(fmaxf(x0.x, x0.y), fmaxf(x0.z, x0.w)),
                    fmaxf(fmaxf(x1.x, x1.y), fmaxf(x1.z, x1.w)));
    red[tid] = m;
    __syncthreads();
    #pragma unroll
    for (int s = 128; s > 0; s >>= 1) {
        if (tid < s) red[tid] = fmaxf(red[tid], red[tid + s]);
        __syncthreads();
    }
    const float rowmax = red[0];
    __syncthreads();

    x0.x = __expf(x0.x - rowmax); x0.y = __expf(x0.y - rowmax);
    x0.z = __expf(x0.z - rowmax); x0.w = __expf(x0.w - rowmax);
    x1.x = __expf(x1.x - rowmax); x1.y = __expf(x1.y - rowmax);
    x1.z = __expf(x1.z - rowmax); x1.w = __expf(x1.w - rowmax);

    red[tid] = (x0.x + x0.y + x0.z + x0.w) + (x1.x + x1.y + x1.z + x1.w);
    __syncthreads();
    #pragma unroll
    for (int s = 128; s > 0; s >>= 1) {
        if (tid < s) red[tid] += red[tid + s];
        __syncthreads();
    }
    const float inv = 1.0f / red[0];

    x0.x *= inv; x0.y *= inv; x0.z *= inv; x0.w *= inv;
    x1.x *= inv; x1.y *= inv; x1.z *= inv; x1.w *= inv;
    p4[tid] = x0;
    p4[tid + 256] = x1;
}

extern "C" void kernel_launch(void* const* d_in, const int* in_sizes, int n_in,
                              void* d_out, int out_size, void* d_ws, size_t ws_size,
                              hipStream_t stream)
{
    const float* key   = (const float*)d_in[0];  // [8,2048,1024]
    const float* query = (const float*)d_in[1];  // [8,2048,1024]
    const float* value = (const float*)d_in[2];  // [8,2048,1024]
    const float* W     = (const float*)d_in[3];  // [1024,1024]
    // d_in[4] = bias: scalar additive shift on scores -> softmax-invariant -> no-op.

    const int B = 8, LQ = 2048, LK = 2048, D = 1024, DV = 1024;

    float* weights = (float*)d_out;                             // B*LQ*LK
    float* ctx     = (float*)d_out + (size_t)B * LQ * LK;       // B*LQ*DV (== qW size)

    // 1) qW = query @ W   -> staged in ctx region (exactly B*LQ*D floats)
    {
        dim3 grid(D / BN, (B * LQ) / BM, 1);
        gemm_nn<<<grid, 256, 0, stream>>>(query, W, ctx, B * LQ, D, D, 0, 0, 0);
    }
    // 2) scores = qW @ key^T  -> weights region
    {
        dim3 grid(LK / BN, LQ / BM, B);
        gemm_nt<<<grid, 256, 0, stream>>>(ctx, key, weights, LQ, LK, D,
                                          (long)LQ * D, (long)LK * D, (long)LQ * LK);
    }
    // 3) softmax rows in place
    softmax_rows<<<B * LQ, 256, 0, stream>>>(weights, LK);
    // 4) ctx = weights @ value  (overwrites qW staging; qW is dead now)
    {
        dim3 grid(DV / BN, LQ / BM, B);
        gemm_nn<<<grid, 256, 0, stream>>>(weights, value, ctx, LQ, DV, LK,
                                          (long)LQ * LK, (long)LK * DV, (long)LQ * DV);
    }
}

// Round 2
// 863.565 us; speedup vs baseline: 2.6345x; 2.6345x over previous
//
#include <hip/hip_runtime.h>

// Attention_65807488909977 — MFMA version.
// B=8, LQ=LK=2048, D=DV=1024. f32 in/out.
// Precision: scores need < ~0.1 abs error at sigma~1024 -> split-bf16 (hi+lo)
// 3-pass MFMA for query@W and qW@key^T; single-pass bf16 for P@V.
// bias = scalar shift on scores -> softmax-invariant -> skipped.

typedef unsigned short ushort_t;
typedef __attribute__((ext_vector_type(8))) short short8;   // 8 bf16 = 4 VGPRs
typedef __attribute__((ext_vector_type(4))) float f32x4;

__device__ __forceinline__ ushort_t f2bf(float f) {
    unsigned u = __float_as_uint(f);
    unsigned r = u + 0x7fff + ((u >> 16) & 1);   // round-to-nearest-even
    return (ushort_t)(r >> 16);
}
__device__ __forceinline__ float bf2f(ushort_t h) {
    return __uint_as_float(((unsigned)h) << 16);
}

__device__ __forceinline__ void gload_lds16(const void* g, void* l) {
    __builtin_amdgcn_global_load_lds(
        (const __attribute__((address_space(1))) unsigned int*)g,
        (__attribute__((address_space(3))) unsigned int*)l,
        16, 0, 0);
}

// ---------------------------------------------------------------------------
// C = A @ Bt^T with split-bf16 3-pass: C = Ah*Bh + Ah*Bl + Al*Bh
// A* : [M][K] bf16 row-major, Bt*: [N][K] bf16 row-major, C: [M][N] f32.
// Block 256 = 4 waves; 128x128 tile; BK=32.
__global__ __launch_bounds__(256) void gemm3x(
    const ushort_t* __restrict__ Ah, const ushort_t* __restrict__ Al,
    const ushort_t* __restrict__ Bh, const ushort_t* __restrict__ Bl,
    float* __restrict__ C, int K, int N, long sA, long sB, long sC)
{
    __shared__ ushort_t sAh[128 * 32], sAl[128 * 32], sBh[128 * 32], sBl[128 * 32];

    const int bz = blockIdx.z;
    Ah += (long)bz * sA; Al += (long)bz * sA;
    Bh += (long)bz * sB; Bl += (long)bz * sB;
    C  += (long)bz * sC;

    const int m0 = blockIdx.y * 128, n0 = blockIdx.x * 128;
    const int tid = threadIdx.x, w = tid >> 6, lane = tid & 63;
    const int wm = (w & 1) * 64, wn = (w >> 1) * 64;
    const int r16 = lane & 15, quad = lane >> 4;

    f32x4 acc[4][4] = {};

    const int c0 = w * 2;               // this wave's 2 staging chunks (of 8)
    const int srow = lane >> 2;         // 0..15 within chunk
    const int scol = (lane & 3) * 8;    // 0,8,16,24

    for (int k0 = 0; k0 < K; k0 += 32) {
        #pragma unroll
        for (int t = 0; t < 2; ++t) {
            const int c = c0 + t;
            const int grow = c * 16 + srow;
            const long ga = (long)(m0 + grow) * K + k0 + scol;
            const long gb = (long)(n0 + grow) * K + k0 + scol;
            gload_lds16(Ah + ga, &sAh[c * 512]);
            gload_lds16(Al + ga, &sAl[c * 512]);
            gload_lds16(Bh + gb, &sBh[c * 512]);
            gload_lds16(Bl + gb, &sBl[c * 512]);
        }
        __syncthreads();   // drains vmcnt before barrier

        short8 a_h[4], a_l[4], b_h[4], b_l[4];
        #pragma unroll
        for (int i = 0; i < 4; ++i) {
            a_h[i] = *(const short8*)&sAh[(wm + i * 16 + r16) * 32 + quad * 8];
            a_l[i] = *(const short8*)&sAl[(wm + i * 16 + r16) * 32 + quad * 8];
            b_h[i] = *(const short8*)&sBh[(wn + i * 16 + r16) * 32 + quad * 8];
            b_l[i] = *(const short8*)&sBl[(wn + i * 16 + r16) * 32 + quad * 8];
        }
        #pragma unroll
        for (int i = 0; i < 4; ++i)
            #pragma unroll
            for (int j = 0; j < 4; ++j) {
                acc[i][j] = __builtin_amdgcn_mfma_f32_16x16x32_bf16(a_h[i], b_h[j], acc[i][j], 0, 0, 0);
                acc[i][j] = __builtin_amdgcn_mfma_f32_16x16x32_bf16(a_h[i], b_l[j], acc[i][j], 0, 0, 0);
                acc[i][j] = __builtin_amdgcn_mfma_f32_16x16x32_bf16(a_l[i], b_h[j], acc[i][j], 0, 0, 0);
            }
        __syncthreads();
    }

    #pragma unroll
    for (int i = 0; i < 4; ++i)
        #pragma unroll
        for (int j = 0; j < 4; ++j)
            #pragma unroll
            for (int r = 0; r < 4; ++r)
                C[(long)(m0 + wm + i * 16 + quad * 4 + r) * N + n0 + wn + j * 16 + r16] = acc[i][j][r];
}

// Single-pass bf16 GEMM, same structure (for P @ V^T_staged).
__global__ __launch_bounds__(256) void gemm1x(
    const ushort_t* __restrict__ A, const ushort_t* __restrict__ Bt,
    float* __restrict__ C, int K, int N, long sA, long sB, long sC)
{
    __shared__ ushort_t sA_[128 * 32], sB_[128 * 32];

    const int bz = blockIdx.z;
    A += (long)bz * sA; Bt += (long)bz * sB; C += (long)bz * sC;

    const int m0 = blockIdx.y * 128, n0 = blockIdx.x * 128;
    const int tid = threadIdx.x, w = tid >> 6, lane = tid & 63;
    const int wm = (w & 1) * 64, wn = (w >> 1) * 64;
    const int r16 = lane & 15, quad = lane >> 4;

    f32x4 acc[4][4] = {};

    const int c0 = w * 2;
    const int srow = lane >> 2;
    const int scol = (lane & 3) * 8;

    for (int k0 = 0; k0 < K; k0 += 32) {
        #pragma unroll
        for (int t = 0; t < 2; ++t) {
            const int c = c0 + t;
            const int grow = c * 16 + srow;
            gload_lds16(A  + (long)(m0 + grow) * K + k0 + scol, &sA_[c * 512]);
            gload_lds16(Bt + (long)(n0 + grow) * K + k0 + scol, &sB_[c * 512]);
        }
        __syncthreads();

        short8 a_[4], b_[4];
        #pragma unroll
        for (int i = 0; i < 4; ++i) {
            a_[i] = *(const short8*)&sA_[(wm + i * 16 + r16) * 32 + quad * 8];
            b_[i] = *(const short8*)&sB_[(wn + i * 16 + r16) * 32 + quad * 8];
        }
        #pragma unroll
        for (int i = 0; i < 4; ++i)
            #pragma unroll
            for (int j = 0; j < 4; ++j)
                acc[i][j] = __builtin_amdgcn_mfma_f32_16x16x32_bf16(a_[i], b_[j], acc[i][j], 0, 0, 0);
        __syncthreads();
    }

    #pragma unroll
    for (int i = 0; i < 4; ++i)
        #pragma unroll
        for (int j = 0; j < 4; ++j)
            #pragma unroll
            for (int r = 0; r < 4; ++r)
                C[(long)(m0 + wm + i * 16 + quad * 4 + r) * N + n0 + wn + j * 16 + r16] = acc[i][j][r];
}

// ---------------------------------------------------------------------------
// x[f32] -> hi = bf16(x), lo = bf16(x - hi). float4-vectorized.
__global__ __launch_bounds__(256) void split_pair(
    const float* __restrict__ x, ushort_t* __restrict__ hi, ushort_t* __restrict__ lo, int n4)
{
    int i = blockIdx.x * 256 + threadIdx.x;
    if (i >= n4) return;
    float4 v = ((const float4*)x)[i];
    ushort4 h, l;
    h.x = f2bf(v.x); l.x = f2bf(v.x - bf2f(h.x));
    h.y = f2bf(v.y); l.y = f2bf(v.y - bf2f(h.y));
    h.z = f2bf(v.z); l.z = f2bf(v.z - bf2f(h.z));
    h.w = f2bf(v.w); l.w = f2bf(v.w - bf2f(h.w));
    ((ushort4*)hi)[i] = h;
    ((ushort4*)lo)[i] = l;
}

// src [R][C] f32 -> dst [C][R] bf16 (batched via blockIdx.z).
__global__ __launch_bounds__(256) void transpose_cvt(
    const float* __restrict__ src, ushort_t* __restrict__ dst,
    int R, int C, long sS, long sD)
{
    __shared__ float t[32][33];
    src += (long)blockIdx.z * sS; dst += (long)blockIdx.z * sD;
    const int r0 = blockIdx.y * 32, c0 = blockIdx.x * 32;
    const int tx = threadIdx.x & 31, ty = threadIdx.x >> 5;  // ty 0..7
    #pragma unroll
    for (int yy = 0; yy < 4; ++yy)
        t[ty + yy * 8][tx] = src[(long)(r0 + ty + yy * 8) * C + c0 + tx];
    __syncthreads();
    #pragma unroll
    for (int yy = 0; yy < 4; ++yy)
        dst[(long)(c0 + ty + yy * 8) * R + r0 + tx] = f2bf(t[tx][ty + yy * 8]);
}

// src [R][C] f32 -> dstH/dstL [C][R] bf16 hi/lo split.
__global__ __launch_bounds__(256) void transpose_split(
    const float* __restrict__ src, ushort_t* __restrict__ dstH, ushort_t* __restrict__ dstL,
    int R, int C)
{
    __shared__ float t[32][33];
    const int r0 = blockIdx.y * 32, c0 = blockIdx.x * 32;
    const int tx = threadIdx.x & 31, ty = threadIdx.x >> 5;
    #pragma unroll
    for (int yy = 0; yy < 4; ++yy)
        t[ty + yy * 8][tx] = src[(long)(r0 + ty + yy * 8) * C + c0 + tx];
    __syncthreads();
    #pragma unroll
    for (int yy = 0; yy < 4; ++yy) {
        float v = t[tx][ty + yy * 8];
        ushort_t h = f2bf(v);
        dstH[(long)(c0 + ty + yy * 8) * R + r0 + tx] = h;
        dstL[(long)(c0 + ty + yy * 8) * R + r0 + tx] = f2bf(v - bf2f(h));
    }
}

// In-place row softmax over L=2048 + bf16 copy of the probabilities.
__global__ __launch_bounds__(256) void softmax_rows(
    float* __restrict__ S, ushort_t* __restrict__ Pb)
{
    __shared__ float red[256];
    const int tid = threadIdx.x;
    float4* p4 = (float4*)(S + (size_t)blockIdx.x * 2048);

    float4 x0 = p4[tid];
    float4 x1 = p4[tid + 256];

    float m = fmaxf(fmaxf(fmaxf(x0.x, x0.y), fmaxf(x0.z, x0.w)),
                    fmaxf(fmaxf(x1.x, x1.y), fmaxf(x1.z, x1.w)));
    red[tid] = m;
    __syncthreads();
    #pragma unroll
    for (int s = 128; s > 0; s >>= 1) {
        if (tid < s) red[tid] = fmaxf(red[tid], red[tid + s]);
        __syncthreads();
    }
    const float rowmax = red[0];
    __syncthreads();

    x0.x = __expf(x0.x - rowmax); x0.y = __expf(x0.y - rowmax);
    x0.z = __expf(x0.z - rowmax); x0.w = __expf(x0.w - rowmax);
    x1.x = __expf(x1.x - rowmax); x1.y = __expf(x1.y - rowmax);
    x1.z = __expf(x1.z - rowmax); x1.w = __expf(x1.w - rowmax);

    red[tid] = (x0.x + x0.y + x0.z + x0.w) + (x1.x + x1.y + x1.z + x1.w);
    __syncthreads();
    #pragma unroll
    for (int s = 128; s > 0; s >>= 1) {
        if (tid < s) red[tid] += red[tid + s];
        __syncthreads();
    }
    const float inv = 1.0f / red[0];

    x0.x *= inv; x0.y *= inv; x0.z *= inv; x0.w *= inv;
    x1.x *= inv; x1.y *= inv; x1.z *= inv; x1.w *= inv;
    p4[tid] = x0;
    p4[tid + 256] = x1;

    ushort4* pb = (ushort4*)(Pb + (size_t)blockIdx.x * 2048);
    ushort4 b0, b1;
    b0.x = f2bf(x0.x); b0.y = f2bf(x0.y); b0.z = f2bf(x0.z); b0.w = f2bf(x0.w);
    b1.x = f2bf(x1.x); b1.y = f2bf(x1.y); b1.z = f2bf(x1.z); b1.w = f2bf(x1.w);
    pb[tid] = b0;
    pb[tid + 256] = b1;
}

// ---------------------------------------------------------------------------
extern "C" void kernel_launch(void* const* d_in, const int* in_sizes, int n_in,
                              void* d_out, int out_size, void* d_ws, size_t ws_size,
                              hipStream_t stream)
{
    const float* key   = (const float*)d_in[0];  // [8,2048,1024]
    const float* query = (const float*)d_in[1];  // [8,2048,1024]
    const float* value = (const float*)d_in[2];  // [8,2048,1024]
    const float* W     = (const float*)d_in[3];  // [1024,1024]
    // d_in[4] (bias): scalar shift on scores -> softmax-invariant -> no-op.

    float* weights = (float*)d_out;                         // 8*2048*2048
    float* ctx     = (float*)d_out + 33554432;              // 8*2048*1024

    ushort_t* Qh  = (ushort_t*)d_ws;          // 16M elems (32 MB)
    ushort_t* Ql  = Qh + 16777216;            // 32 MB
    ushort_t* Kh  = Qh + 33554432;            // 32 MB
    ushort_t* Kl  = Qh + 50331648;            // 32 MB
    ushort_t* Wth = Qh + 67108864;            // 2 MB
    ushort_t* Wtl = Qh + 68157440;            // 2 MB  (total 132 MB)
    ushort_t* Pb  = Kh;                       // reuse (Kh/Kl dead after scores)
    ushort_t* Vt  = Qh;                       // reuse (qW splits dead after scores)

    // 1) W -> Wt hi/lo (transposed to [N][K])
    transpose_split<<<dim3(32, 32, 1), 256, 0, stream>>>(W, Wth, Wtl, 1024, 1024);
    // 2) query, key -> hi/lo splits
    split_pair<<<16384, 256, 0, stream>>>(query, Qh, Ql, 4194304);
    split_pair<<<16384, 256, 0, stream>>>(key, Kh, Kl, 4194304);
    // 3) qW = query @ W  (f32, staged in ctx region)   M=16384 N=1024 K=1024
    gemm3x<<<dim3(8, 128, 1), 256, 0, stream>>>(Qh, Ql, Wth, Wtl, ctx, 1024, 1024, 0, 0, 0);
    // 4) qW -> hi/lo (into Qh/Ql)
    split_pair<<<16384, 256, 0, stream>>>(ctx, Qh, Ql, 4194304);
    // 5) scores = qW @ key^T   per-batch M=2048 N=2048 K=1024
    gemm3x<<<dim3(16, 16, 8), 256, 0, stream>>>(Qh, Ql, Kh, Kl, weights, 1024, 2048,
                                                2048L * 1024, 2048L * 1024, 2048L * 2048);
    // 6) softmax rows in place + bf16 copy
    softmax_rows<<<16384, 256, 0, stream>>>(weights, Pb);
    // 7) value -> Vt [DV][LK] bf16 per batch
    transpose_cvt<<<dim3(32, 64, 8), 256, 0, stream>>>(value, Vt, 2048, 1024,
                                                       2048L * 1024, 1024L * 2048);
    // 8) ctx = P @ V   per-batch M=2048 N=1024 K=2048  (overwrites qW staging)
    gemm1x<<<dim3(8, 16, 8), 256, 0, stream>>>(Pb, Vt, ctx, 2048, 1024,
                                               2048L * 2048, 2048L * 1024, 2048L * 1024);
}

// Round 3
// 828.437 us; speedup vs baseline: 2.7462x; 1.0424x over previous
//
#include <hip/hip_runtime.h>

// Attention_65807488909977 — MFMA 32x32x16 version.
// B=8, LQ=LK=2048, D=DV=1024. f32 in/out.
// scores need <~0.1 abs error at sigma~1024 -> split-bf16 (hi+lo) 3-pass MFMA
// for query@W and qW@key^T; single-pass bf16 for P@V.
// bias = scalar shift on scores -> softmax-invariant -> skipped.
// Buffer plan:
//   ws:  Qh Ql Kh Kl (32MB each) + Wth Wtl (2MB each) = 132 MB
//   qW hi/lo -> d_out ctx region (64MB, dead until final P@V write)
//   Pb -> Kh region (dead after scores); Vt -> Qh region (dead after qW gemm)

typedef unsigned short ushort_t;
typedef __attribute__((ext_vector_type(8))) short short8;    // 8 bf16 = 4 VGPRs
typedef __attribute__((ext_vector_type(16))) float f32x16;   // 32x32 acc

__device__ __forceinline__ ushort_t f2bf(float f) {
    unsigned u = __float_as_uint(f);
    unsigned r = u + 0x7fff + ((u >> 16) & 1);   // round-to-nearest-even
    return (ushort_t)(r >> 16);
}
__device__ __forceinline__ float bf2f(ushort_t h) {
    return __uint_as_float(((unsigned)h) << 16);
}

__device__ __forceinline__ void gload_lds16(const void* g, void* l) {
    __builtin_amdgcn_global_load_lds(
        (const __attribute__((address_space(1))) unsigned int*)g,
        (__attribute__((address_space(3))) unsigned int*)l,
        16, 0, 0);
}

// ---------------------------------------------------------------------------
// Shared K-loop body: 128x128 tile, BK=32, 4 waves (each 64x64 = 2x2 of 32x32).
// 3-pass split-bf16: acc += Ah*Bh + Ah*Bl + Al*Bh.
#define GEMM3X_BODY(EPILOGUE)                                                     \
    __shared__ ushort_t sAh[128 * 32], sAl[128 * 32], sBh[128 * 32], sBl[128 * 32];\
    const int bz = blockIdx.z;                                                    \
    Ah += (long)bz * sA; Al += (long)bz * sA;                                     \
    Bh += (long)bz * sB; Bl += (long)bz * sB;                                     \
    const int m0 = blockIdx.y * 128, n0 = blockIdx.x * 128;                       \
    const int tid = threadIdx.x, w = tid >> 6, lane = tid & 63;                   \
    const int wm = (w & 1) * 64, wn = (w >> 1) * 64;                              \
    const int l31 = lane & 31, half = lane >> 5;                                  \
    f32x16 acc[2][2] = {};                                                        \
    const int c0 = w * 2;                                                         \
    const int srow = lane >> 2, scol = (lane & 3) * 8;                            \
    for (int k0 = 0; k0 < K; k0 += 32) {                                          \
        _Pragma("unroll")                                                         \
        for (int t = 0; t < 2; ++t) {                                             \
            const int c = c0 + t;                                                 \
            const int grow = c * 16 + srow;                                       \
            const long ga = (long)(m0 + grow) * K + k0 + scol;                    \
            const long gb = (long)(n0 + grow) * K + k0 + scol;                    \
            gload_lds16(Ah + ga, &sAh[c * 512]);                                  \
            gload_lds16(Al + ga, &sAl[c * 512]);                                  \
            gload_lds16(Bh + gb, &sBh[c * 512]);                                  \
            gload_lds16(Bl + gb, &sBl[c * 512]);                                  \
        }                                                                         \
        __syncthreads();                                                          \
        _Pragma("unroll")                                                         \
        for (int s = 0; s < 2; ++s) {                                             \
            short8 a_h[2], a_l[2], b_h[2], b_l[2];                                \
            const int ko = s * 16 + half * 8;                                     \
            _Pragma("unroll")                                                     \
            for (int i = 0; i < 2; ++i) {                                         \
                a_h[i] = *(const short8*)&sAh[(wm + i * 32 + l31) * 32 + ko];     \
                a_l[i] = *(const short8*)&sAl[(wm + i * 32 + l31) * 32 + ko];     \
                b_h[i] = *(const short8*)&sBh[(wn + i * 32 + l31) * 32 + ko];     \
                b_l[i] = *(const short8*)&sBl[(wn + i * 32 + l31) * 32 + ko];     \
            }                                                                     \
            _Pragma("unroll")                                                     \
            for (int i = 0; i < 2; ++i)                                           \
                _Pragma("unroll")                                                 \
                for (int j = 0; j < 2; ++j) {                                     \
                    acc[i][j] = __builtin_amdgcn_mfma_f32_32x32x16_bf16(a_h[i], b_h[j], acc[i][j], 0, 0, 0); \
                    acc[i][j] = __builtin_amdgcn_mfma_f32_32x32x16_bf16(a_h[i], b_l[j], acc[i][j], 0, 0, 0); \
                    acc[i][j] = __builtin_amdgcn_mfma_f32_32x32x16_bf16(a_l[i], b_h[j], acc[i][j], 0, 0, 0); \
                }                                                                 \
        }                                                                         \
        __syncthreads();                                                          \
    }                                                                             \
    EPILOGUE

// f32 output epilogue
__global__ __launch_bounds__(256) void gemm3x_f32(
    const ushort_t* __restrict__ Ah, const ushort_t* __restrict__ Al,
    const ushort_t* __restrict__ Bh, const ushort_t* __restrict__ Bl,
    float* __restrict__ C, int K, int N, long sA, long sB, long sC)
{
    GEMM3X_BODY({
        C += (long)bz * sC;
        _Pragma("unroll")
        for (int i = 0; i < 2; ++i)
            _Pragma("unroll")
            for (int j = 0; j < 2; ++j)
                _Pragma("unroll")
                for (int r = 0; r < 16; ++r) {
                    const int row = wm + i * 32 + (r & 3) + 8 * (r >> 2) + 4 * half;
                    const int col = wn + j * 32 + l31;
                    C[(long)(m0 + row) * N + n0 + col] = acc[i][j][r];
                }
    })
}

// bf16 hi/lo split output epilogue (for qW = query @ W)
__global__ __launch_bounds__(256) void gemm3x_split(
    const ushort_t* __restrict__ Ah, const ushort_t* __restrict__ Al,
    const ushort_t* __restrict__ Bh, const ushort_t* __restrict__ Bl,
    ushort_t* __restrict__ Ch, ushort_t* __restrict__ Cl, int K, int N,
    long sA, long sB, long sC)
{
    GEMM3X_BODY({
        Ch += (long)bz * sC; Cl += (long)bz * sC;
        _Pragma("unroll")
        for (int i = 0; i < 2; ++i)
            _Pragma("unroll")
            for (int j = 0; j < 2; ++j)
                _Pragma("unroll")
                for (int r = 0; r < 16; ++r) {
                    const int row = wm + i * 32 + (r & 3) + 8 * (r >> 2) + 4 * half;
                    const int col = wn + j * 32 + l31;
                    const long o = (long)(m0 + row) * N + n0 + col;
                    float x = acc[i][j][r];
                    ushort_t h = f2bf(x);
                    Ch[o] = h;
                    Cl[o] = f2bf(x - bf2f(h));
                }
    })
}

// ---------------------------------------------------------------------------
// Single-pass bf16 GEMM for P @ V (both [rows][K] bf16), with XCD-grouping
// swizzle: the 8 N-blocks sharing a P row-strip map to ids with equal (id%8)
// -> same XCD -> P strip served from that XCD's L2.
// Launched 1-D with gx*gy*gz blocks; logical grid (gx=8 n-blocks, gy m-blocks, gz batch).
__global__ __launch_bounds__(256) void gemm1x(
    const ushort_t* __restrict__ A, const ushort_t* __restrict__ Bt,
    float* __restrict__ C, int K, int N, long sA, long sB, long sC, int gy)
{
    const int id = blockIdx.x;
    const int xcd = id & 7, t = id >> 3;
    const int bx = t & 7, rest = t >> 3;
    const int strip = xcd + 8 * rest;          // 0 .. gy*gz-1
    const int by = strip % gy, bz = strip / gy;

    __shared__ ushort_t sA_[128 * 32], sB_[128 * 32];

    A += (long)bz * sA; Bt += (long)bz * sB; C += (long)bz * sC;

    const int m0 = by * 128, n0 = bx * 128;
    const int tid = threadIdx.x, w = tid >> 6, lane = tid & 63;
    const int wm = (w & 1) * 64, wn = (w >> 1) * 64;
    const int l31 = lane & 31, half = lane >> 5;

    f32x16 acc[2][2] = {};

    const int c0 = w * 2;
    const int srow = lane >> 2, scol = (lane & 3) * 8;

    for (int k0 = 0; k0 < K; k0 += 32) {
        #pragma unroll
        for (int t2 = 0; t2 < 2; ++t2) {
            const int c = c0 + t2;
            const int grow = c * 16 + srow;
            gload_lds16(A  + (long)(m0 + grow) * K + k0 + scol, &sA_[c * 512]);
            gload_lds16(Bt + (long)(n0 + grow) * K + k0 + scol, &sB_[c * 512]);
        }
        __syncthreads();
        #pragma unroll
        for (int s = 0; s < 2; ++s) {
            short8 a_[2], b_[2];
            const int ko = s * 16 + half * 8;
            #pragma unroll
            for (int i = 0; i < 2; ++i) {
                a_[i] = *(const short8*)&sA_[(wm + i * 32 + l31) * 32 + ko];
                b_[i] = *(const short8*)&sB_[(wn + i * 32 + l31) * 32 + ko];
            }
            #pragma unroll
            for (int i = 0; i < 2; ++i)
                #pragma unroll
                for (int j = 0; j < 2; ++j)
                    acc[i][j] = __builtin_amdgcn_mfma_f32_32x32x16_bf16(a_[i], b_[j], acc[i][j], 0, 0, 0);
        }
        __syncthreads();
    }

    #pragma unroll
    for (int i = 0; i < 2; ++i)
        #pragma unroll
        for (int j = 0; j < 2; ++j)
            #pragma unroll
            for (int r = 0; r < 16; ++r) {
                const int row = wm + i * 32 + (r & 3) + 8 * (r >> 2) + 4 * half;
                const int col = wn + j * 32 + l31;
                C[(long)(m0 + row) * N + n0 + col] = acc[i][j][r];
            }
}

// ---------------------------------------------------------------------------
// x[f32] -> hi = bf16(x), lo = bf16(x - hi). float4-vectorized.
__global__ __launch_bounds__(256) void split_pair(
    const float* __restrict__ x, ushort_t* __restrict__ hi, ushort_t* __restrict__ lo, int n4)
{
    int i = blockIdx.x * 256 + threadIdx.x;
    if (i >= n4) return;
    float4 v = ((const float4*)x)[i];
    ushort4 h, l;
    h.x = f2bf(v.x); l.x = f2bf(v.x - bf2f(h.x));
    h.y = f2bf(v.y); l.y = f2bf(v.y - bf2f(h.y));
    h.z = f2bf(v.z); l.z = f2bf(v.z - bf2f(h.z));
    h.w = f2bf(v.w); l.w = f2bf(v.w - bf2f(h.w));
    ((ushort4*)hi)[i] = h;
    ((ushort4*)lo)[i] = l;
}

// src [R][C] f32 -> dst [C][R] bf16 (batched via blockIdx.z).
__global__ __launch_bounds__(256) void transpose_cvt(
    const float* __restrict__ src, ushort_t* __restrict__ dst,
    int R, int C, long sS, long sD)
{
    __shared__ float t[32][33];
    src += (long)blockIdx.z * sS; dst += (long)blockIdx.z * sD;
    const int r0 = blockIdx.y * 32, c0 = blockIdx.x * 32;
    const int tx = threadIdx.x & 31, ty = threadIdx.x >> 5;  // ty 0..7
    #pragma unroll
    for (int yy = 0; yy < 4; ++yy)
        t[ty + yy * 8][tx] = src[(long)(r0 + ty + yy * 8) * C + c0 + tx];
    __syncthreads();
    #pragma unroll
    for (int yy = 0; yy < 4; ++yy)
        dst[(long)(c0 + ty + yy * 8) * R + r0 + tx] = f2bf(t[tx][ty + yy * 8]);
}

// src [R][C] f32 -> dstH/dstL [C][R] bf16 hi/lo split.
__global__ __launch_bounds__(256) void transpose_split(
    const float* __restrict__ src, ushort_t* __restrict__ dstH, ushort_t* __restrict__ dstL,
    int R, int C)
{
    __shared__ float t[32][33];
    const int r0 = blockIdx.y * 32, c0 = blockIdx.x * 32;
    const int tx = threadIdx.x & 31, ty = threadIdx.x >> 5;
    #pragma unroll
    for (int yy = 0; yy < 4; ++yy)
        t[ty + yy * 8][tx] = src[(long)(r0 + ty + yy * 8) * C + c0 + tx];
    __syncthreads();
    #pragma unroll
    for (int yy = 0; yy < 4; ++yy) {
        float v = t[tx][ty + yy * 8];
        ushort_t h = f2bf(v);
        dstH[(long)(c0 + ty + yy * 8) * R + r0 + tx] = h;
        dstL[(long)(c0 + ty + yy * 8) * R + r0 + tx] = f2bf(v - bf2f(h));
    }
}

// In-place row softmax over L=2048 + bf16 copy of the probabilities.
__global__ __launch_bounds__(256) void softmax_rows(
    float* __restrict__ S, ushort_t* __restrict__ Pb)
{
    __shared__ float red[256];
    const int tid = threadIdx.x;
    float4* p4 = (float4*)(S + (size_t)blockIdx.x * 2048);

    float4 x0 = p4[tid];
    float4 x1 = p4[tid + 256];

    float m = fmaxf(fmaxf(fmaxf(x0.x, x0.y), fmaxf(x0.z, x0.w)),
                    fmaxf(fmaxf(x1.x, x1.y), fmaxf(x1.z, x1.w)));
    red[tid] = m;
    __syncthreads();
    #pragma unroll
    for (int s = 128; s > 0; s >>= 1) {
        if (tid < s) red[tid] = fmaxf(red[tid], red[tid + s]);
        __syncthreads();
    }
    const float rowmax = red[0];
    __syncthreads();

    x0.x = __expf(x0.x - rowmax); x0.y = __expf(x0.y - rowmax);
    x0.z = __expf(x0.z - rowmax); x0.w = __expf(x0.w - rowmax);
    x1.x = __expf(x1.x - rowmax); x1.y = __expf(x1.y - rowmax);
    x1.z = __expf(x1.z - rowmax); x1.w = __expf(x1.w - rowmax);

    red[tid] = (x0.x + x0.y + x0.z + x0.w) + (x1.x + x1.y + x1.z + x1.w);
    __syncthreads();
    #pragma unroll
    for (int s = 128; s > 0; s >>= 1) {
        if (tid < s) red[tid] += red[tid + s];
        __syncthreads();
    }
    const float inv = 1.0f / red[0];

    x0.x *= inv; x0.y *= inv; x0.z *= inv; x0.w *= inv;
    x1.x *= inv; x1.y *= inv; x1.z *= inv; x1.w *= inv;
    p4[tid] = x0;
    p4[tid + 256] = x1;

    ushort4* pb = (ushort4*)(Pb + (size_t)blockIdx.x * 2048);
    ushort4 b0, b1;
    b0.x = f2bf(x0.x); b0.y = f2bf(x0.y); b0.z = f2bf(x0.z); b0.w = f2bf(x0.w);
    b1.x = f2bf(x1.x); b1.y = f2bf(x1.y); b1.z = f2bf(x1.z); b1.w = f2bf(x1.w);
    pb[tid] = b0;
    pb[tid + 256] = b1;
}

// ---------------------------------------------------------------------------
extern "C" void kernel_launch(void* const* d_in, const int* in_sizes, int n_in,
                              void* d_out, int out_size, void* d_ws, size_t ws_size,
                              hipStream_t stream)
{
    const float* key   = (const float*)d_in[0];  // [8,2048,1024]
    const float* query = (const float*)d_in[1];  // [8,2048,1024]
    const float* value = (const float*)d_in[2];  // [8,2048,1024]
    const float* W     = (const float*)d_in[3];  // [1024,1024]
    // d_in[4] (bias): scalar shift on scores -> softmax-invariant -> no-op.

    float* weights = (float*)d_out;                         // 8*2048*2048 f32
    float* ctx     = (float*)d_out + 33554432;              // 8*2048*1024 f32

    ushort_t* Qh  = (ushort_t*)d_ws;          // 16M elems (32 MB)
    ushort_t* Ql  = Qh + 16777216;
    ushort_t* Kh  = Qh + 33554432;
    ushort_t* Kl  = Qh + 50331648;
    ushort_t* Wth = Qh + 67108864;            // 2 MB
    ushort_t* Wtl = Qh + 68157440;            // 2 MB  (ws total 132 MB)
    ushort_t* qWh = (ushort_t*)ctx;           // 32 MB  (ctx region is free
    ushort_t* qWl = qWh + 16777216;           //         until final P@V write)
    ushort_t* Pb  = Kh;                       // reuse (Kh/Kl dead after scores)
    ushort_t* Vt  = Qh;                       // reuse (Qh/Ql dead after qW gemm)

    // 1) W -> Wt hi/lo (transposed to [N][K])
    transpose_split<<<dim3(32, 32, 1), 256, 0, stream>>>(W, Wth, Wtl, 1024, 1024);
    // 2) query, key -> hi/lo splits
    split_pair<<<16384, 256, 0, stream>>>(query, Qh, Ql, 4194304);
    split_pair<<<16384, 256, 0, stream>>>(key, Kh, Kl, 4194304);
    // 3) qW = query @ W -> bf16 hi/lo directly (fused split)  M=16384 N=1024 K=1024
    gemm3x_split<<<dim3(8, 128, 1), 256, 0, stream>>>(Qh, Ql, Wth, Wtl, qWh, qWl,
                                                      1024, 1024, 0, 0, 0);
    // 4) scores = qW @ key^T   per-batch M=2048 N=2048 K=1024
    gemm3x_f32<<<dim3(16, 16, 8), 256, 0, stream>>>(qWh, qWl, Kh, Kl, weights, 1024, 2048,
                                                    2048L * 1024, 2048L * 1024, 2048L * 2048);
    // 5) softmax rows in place + bf16 copy
    softmax_rows<<<16384, 256, 0, stream>>>(weights, Pb);
    // 6) value -> Vt [DV][LK] bf16 per batch
    transpose_cvt<<<dim3(32, 64, 8), 256, 0, stream>>>(value, Vt, 2048, 1024,
                                                       2048L * 1024, 1024L * 2048);
    // 7) ctx = P @ V   per-batch M=2048 N=1024 K=2048 (XCD-swizzled 1-D grid)
    gemm1x<<<dim3(8 * 16 * 8, 1, 1), 256, 0, stream>>>(Pb, Vt, ctx, 2048, 1024,
                                                       2048L * 2048, 2048L * 1024,
                                                       2048L * 1024, 16);
}